// Round 1
// baseline (290.711 us; speedup 1.0000x reference)
//
#include <hip/hip_runtime.h>

#define T_DIM 20
#define K_DIM 50
#define V_DIM 50000
#define D_DIM 200
#define NEG_TOPK 20
#define M_DIM (K_DIM * NEG_TOPK)   // 1000 candidates per time slice
#define TEMP_INV (1.0f / 0.07f)

// ---------------------------------------------------------------------------
// Kernel 1: exact top-20 indices of beta[row, :] for each row = t*K + k.
// Keys pack (monotonic-float, inverted index) into u64 so that
// key order == (value desc, index asc) — matches jax.lax.top_k tie-breaking.
// Per-thread sorted top-20 in registers (all compile-time indices), with a
// block-shared monotone threshold (max over lanes of each lane's 20th best —
// a proven lower bound on the global 20th) to prune the insert path.
// ---------------------------------------------------------------------------
__global__ __launch_bounds__(256) void topk_kernel(const float* __restrict__ beta,
                                                   int* __restrict__ topk_idx) {
  const int row  = blockIdx.x;          // 0..999
  const int tid  = threadIdx.x;
  const int lane = tid & 63;
  const int wid  = tid >> 6;
  const float4* __restrict__ b4 = (const float4*)(beta + (size_t)row * V_DIM);

  unsigned long long kk[NEG_TOPK];
#pragma unroll
  for (int j = 0; j < NEG_TOPK; ++j) kk[j] = 0ull;

  __shared__ unsigned s_thr;
  if (tid == 0) s_thr = 0u;
  __syncthreads();

  unsigned thr = 0u;
  int it = 0;
  for (int i = tid; i < V_DIM / 4; i += 256) {
    float4 v = b4[i];
    const int base = i * 4;
#pragma unroll
    for (int e = 0; e < 4; ++e) {
      float f = (e == 0) ? v.x : (e == 1) ? v.y : (e == 2) ? v.z : v.w;
      unsigned u  = __float_as_uint(f);
      unsigned mv = ((int)u < 0) ? ~u : (u | 0x80000000u);
      if (mv >= thr) {
        unsigned long long key =
            ((unsigned long long)mv << 32) |
            (unsigned long long)(0xFFFFFFFFu - (unsigned)(base + e));
        if (key > kk[NEG_TOPK - 1]) {
          unsigned long long c = key;
#pragma unroll
          for (int j = 0; j < NEG_TOPK; ++j) {   // unrolled insertion: static idx only
            unsigned long long cur = kk[j];
            bool ins = c > cur;
            unsigned long long nj = ins ? c : cur;
            c = ins ? cur : c;
            kk[j] = nj;
          }
        }
      }
    }
    // refresh shared threshold every 8 iterations (uniform across waves:
    // every thread runs >= 48 iterations; the divergent 49th has no shfl)
    if ((++it & 7) == 0) {
      unsigned myt = (unsigned)(kk[NEG_TOPK - 1] >> 32);
#pragma unroll
      for (int off = 32; off; off >>= 1) {
        unsigned o = __shfl_xor(myt, off, 64);
        myt = o > myt ? o : myt;
      }
      if (lane == 0) atomicMax(&s_thr, myt);
      thr = *(volatile unsigned*)&s_thr;   // monotone: stale read only loosens
    }
  }

  __syncthreads();

  // 20 tournament rounds across 256 sorted register lists (heads = kk[0]).
  __shared__ unsigned long long wmax[4];
  for (int r = 0; r < NEG_TOPK; ++r) {
    unsigned long long k = kk[0];
#pragma unroll
    for (int off = 32; off; off >>= 1) {
      unsigned long long o = __shfl_xor(k, off, 64);
      if (o > k) k = o;
    }
    if (lane == 0) wmax[wid] = k;
    __syncthreads();
    unsigned long long bmax = wmax[0];
#pragma unroll
    for (int w = 1; w < 4; ++w) bmax = wmax[w] > bmax ? wmax[w] : bmax;
    if (kk[0] == bmax) {                 // keys unique -> exactly one winner
#pragma unroll
      for (int j = 0; j < NEG_TOPK - 1; ++j) kk[j] = kk[j + 1];
      kk[NEG_TOPK - 1] = 0ull;
    }
    if (tid == 0)
      topk_idx[row * NEG_TOPK + r] =
          (int)(0xFFFFFFFFu - (unsigned)(bmax & 0xFFFFFFFFull));
    __syncthreads();
  }
}

// ---------------------------------------------------------------------------
// Kernel 2: per time slice t, build the unique valid candidate list:
// word w is valid iff time_wordcount[t,w]==0; duplicates count once
// (set semantics — which occurrence survives doesn't affect the loss).
// ---------------------------------------------------------------------------
#define BM_WORDS ((V_DIM + 31) / 32)    // 1563
__global__ __launch_bounds__(256) void build_valid_kernel(const int* __restrict__ wc,
                                                          const int* __restrict__ topk,
                                                          int* __restrict__ vlist,
                                                          int* __restrict__ vcnt) {
  const int t = blockIdx.x;
  __shared__ unsigned bm[BM_WORDS];
  __shared__ int cnt;
  for (int i = threadIdx.x; i < BM_WORDS; i += 256) bm[i] = 0u;
  if (threadIdx.x == 0) cnt = 0;
  __syncthreads();
  for (int c = threadIdx.x; c < M_DIM; c += 256) {
    int w = topk[t * M_DIM + c];
    if (wc[t * V_DIM + w] == 0) {
      unsigned bit = 1u << (w & 31);
      unsigned old = atomicOr(&bm[w >> 5], bit);
      if (!(old & bit)) {
        int p = atomicAdd(&cnt, 1);
        vlist[t * M_DIM + p] = w;
      }
    }
  }
  __syncthreads();
  if (threadIdx.x == 0) vcnt[t] = cnt;
}

// ---------------------------------------------------------------------------
// Kernel 3: per row = t*K + k, logsumexp over valid candidates of
// dot(topic_emb[t,k,:], word_emb[w,:]) / 0.07.
// ---------------------------------------------------------------------------
__global__ __launch_bounds__(256) void lse_kernel(const float* __restrict__ temb,
                                                  const float* __restrict__ wemb,
                                                  const int* __restrict__ vlist,
                                                  const int* __restrict__ vcnt,
                                                  float* __restrict__ lse_out) {
  const int row  = blockIdx.x;
  const int t    = row / K_DIM;
  const int tid  = threadIdx.x;
  const int lane = tid & 63;
  const int wid  = tid >> 6;
  const int cnt  = vcnt[t];

  __shared__ float4 tv[D_DIM / 4];   // topic embedding row (broadcast reads)
  __shared__ float  sim[M_DIM];
  __shared__ float  rbuf[8];

  if (cnt == 0) {                    // uniform for the whole block
    if (tid == 0) lse_out[row] = 0.0f;
    return;
  }

  if (tid < D_DIM / 4)
    tv[tid] = ((const float4*)(temb + (size_t)row * D_DIM))[tid];
  __syncthreads();

  for (int c = tid; c < cnt; c += 256) {
    int w = vlist[t * M_DIM + c];
    const float4* wr = (const float4*)(wemb + (size_t)w * D_DIM);
    float acc = 0.f;
#pragma unroll
    for (int d = 0; d < D_DIM / 4; ++d) {
      float4 a = tv[d];
      float4 b = wr[d];
      acc = fmaf(a.x, b.x, acc);
      acc = fmaf(a.y, b.y, acc);
      acc = fmaf(a.z, b.z, acc);
      acc = fmaf(a.w, b.w, acc);
    }
    sim[c] = acc * TEMP_INV;
  }
  __syncthreads();

  float m = -3.0e38f;
  for (int c = tid; c < cnt; c += 256) m = fmaxf(m, sim[c]);
#pragma unroll
  for (int off = 32; off; off >>= 1) m = fmaxf(m, __shfl_xor(m, off, 64));
  if (lane == 0) rbuf[wid] = m;
  __syncthreads();
  m = fmaxf(fmaxf(rbuf[0], rbuf[1]), fmaxf(rbuf[2], rbuf[3]));

  float s = 0.f;
  for (int c = tid; c < cnt; c += 256) s += expf(sim[c] - m);
#pragma unroll
  for (int off = 32; off; off >>= 1) s += __shfl_xor(s, off, 64);
  if (lane == 0) rbuf[4 + wid] = s;
  __syncthreads();
  if (tid == 0) {
    float tot = rbuf[4] + rbuf[5] + rbuf[6] + rbuf[7];
    lse_out[row] = m + logf(tot);
  }
}

// ---------------------------------------------------------------------------
// Kernel 4: final scalar. loss = sum_t(mean_k lse) / count(t with any valid).
// ---------------------------------------------------------------------------
__global__ void final_kernel(const float* __restrict__ lse,
                             const int* __restrict__ vcnt,
                             float* __restrict__ out) {
  const int t = threadIdx.x;           // 64 threads, t < 20 active
  float loss = 0.f, flag = 0.f;
  if (t < T_DIM && vcnt[t] > 0) {
    float s = 0.f;
    for (int k = 0; k < K_DIM; ++k) s += lse[t * K_DIM + k];
    loss = s * (1.0f / K_DIM);
    flag = 1.f;
  }
#pragma unroll
  for (int off = 32; off; off >>= 1) {
    loss += __shfl_down(loss, off, 64);
    flag += __shfl_down(flag, off, 64);
  }
  if (t == 0)
    out[0] = (flag > 0.f) ? loss * (1.0f / fmaxf(flag, 1.f)) : 0.f;  // WEIGHT_UWE=1
}

// ---------------------------------------------------------------------------
extern "C" void kernel_launch(void* const* d_in, const int* in_sizes, int n_in,
                              void* d_out, int out_size, void* d_ws, size_t ws_size,
                              hipStream_t stream) {
  const int*   wc   = (const int*)d_in[0];    // time_wordcount [T,V] int32
  const float* beta = (const float*)d_in[1];  // beta [T,K,V] f32
  const float* temb = (const float*)d_in[2];  // topic_embeddings [T,K,D] f32
  const float* wemb = (const float*)d_in[3];  // word_embeddings [V,D] f32

  // ws layout (16B aligned chunks): topk 80000B | vlist 80000B | vcnt 128B | lse 4000B
  char* ws = (char*)d_ws;
  int*   topk_idx = (int*)(ws + 0);
  int*   vlist    = (int*)(ws + 80000);
  int*   vcnt     = (int*)(ws + 160000);
  float* lse      = (float*)(ws + 160128);
  float* out      = (float*)d_out;

  topk_kernel<<<T_DIM * K_DIM, 256, 0, stream>>>(beta, topk_idx);
  build_valid_kernel<<<T_DIM, 256, 0, stream>>>(wc, topk_idx, vlist, vcnt);
  lse_kernel<<<T_DIM * K_DIM, 256, 0, stream>>>(temb, wemb, vlist, vcnt, lse);
  final_kernel<<<1, 64, 0, stream>>>(lse, vcnt, out);
}

// Round 2
// 112.745 us; speedup vs baseline: 2.5785x; 2.5785x over previous
//
#include <hip/hip_runtime.h>

#define T_DIM 20
#define K_DIM 50
#define V_DIM 50000
#define D_DIM 200
#define NEG_TOPK 20
#define M_DIM (K_DIM * NEG_TOPK)   // 1000 candidates per time slice
#define TEMP_INV (1.0f / 0.07f)
#define POOL_CAP 1024
#define STATIC_THR 3.0f            // pool keeps all elements >= 3.0

// monotone key: order(key) == (value desc, index asc) matches jax.lax.top_k
__device__ __forceinline__ unsigned long long make_key(float f, int idx) {
  unsigned u  = __float_as_uint(f);
  unsigned mv = ((int)u < 0) ? ~u : (u | 0x80000000u);
  return ((unsigned long long)mv << 32) |
         (unsigned long long)(0xFFFFFFFFu - (unsigned)idx);
}

__device__ __forceinline__ unsigned long long wave_max_u64(unsigned long long k) {
#pragma unroll
  for (int off = 32; off; off >>= 1) {
    unsigned long long o = __shfl_xor(k, off, 64);
    if (o > k) k = o;
  }
  return k;
}

// ---------------------------------------------------------------------------
// Kernel 1: exact top-20 per row = t*K+k.
// Fast path: scan row once (1 cmp/element), append elements >= 3.0 to an LDS
// pool; if 20 <= |pool| <= CAP the exact top-20 is in the pool (proof: if >=20
// elements are >= 3.0 then the 20th-largest >= 3.0, so top-20 subset of pool).
// Slow path (exactness guard, never hit on N(0,1) rows): 20 rounds of
// block-wide argmax over the (L2-hot) row with strict-key exclusion.
// ---------------------------------------------------------------------------
__global__ __launch_bounds__(512) void topk_kernel(const float* __restrict__ beta,
                                                   int* __restrict__ topk_idx) {
  const int row  = blockIdx.x;          // 0..999
  const int tid  = threadIdx.x;
  const int lane = tid & 63;
  const int wid  = tid >> 6;
  const float4* __restrict__ b4 = (const float4*)(beta + (size_t)row * V_DIM);

  __shared__ unsigned long long pool[POOL_CAP];
  __shared__ int cnt;
  __shared__ unsigned long long wmax[8];
  if (tid == 0) cnt = 0;
  __syncthreads();

  // ---- scan: 1 compare per element, rare append ----
  for (int i = tid; i < V_DIM / 4; i += 512) {
    float4 v = b4[i];
    const int base = i * 4;
#pragma unroll
    for (int e = 0; e < 4; ++e) {
      float f = (e == 0) ? v.x : (e == 1) ? v.y : (e == 2) ? v.z : v.w;
      if (f >= STATIC_THR) {
        int p = atomicAdd(&cnt, 1);
        if (p < POOL_CAP) pool[p] = make_key(f, base + e);
      }
    }
  }
  __syncthreads();
  const int count = cnt;

  if (count >= NEG_TOPK && count <= POOL_CAP) {
    // ---- fast path: top-20 of <=1024 pooled keys ----
    unsigned long long it0 = 0ull, it1 = 0ull;
    if (tid < count)       it0 = pool[tid];
    if (tid + 512 < count) it1 = pool[tid + 512];
    unsigned long long kprev = ~0ull;
    for (int r = 0; r < NEG_TOPK; ++r) {
      unsigned long long b = 0ull;
      if (it0 < kprev && it0 > b) b = it0;
      if (it1 < kprev && it1 > b) b = it1;
      b = wave_max_u64(b);
      if (lane == 0) wmax[wid] = b;
      __syncthreads();
      unsigned long long bmax = wmax[0];
#pragma unroll
      for (int w = 1; w < 8; ++w) bmax = wmax[w] > bmax ? wmax[w] : bmax;
      if (tid == 0)
        topk_idx[row * NEG_TOPK + r] =
            (int)(0xFFFFFFFFu - (unsigned)(bmax & 0xFFFFFFFFull));
      kprev = bmax;
      __syncthreads();
    }
  } else {
    // ---- slow path: 20 rounds of block argmax over the row (L2-hot) ----
    unsigned long long kprev = ~0ull;
    for (int r = 0; r < NEG_TOPK; ++r) {
      unsigned long long b = 0ull;
      for (int i = tid; i < V_DIM / 4; i += 512) {
        float4 v = b4[i];
        const int base = i * 4;
#pragma unroll
        for (int e = 0; e < 4; ++e) {
          float f = (e == 0) ? v.x : (e == 1) ? v.y : (e == 2) ? v.z : v.w;
          unsigned long long k = make_key(f, base + e);
          if (k < kprev && k > b) b = k;
        }
      }
      b = wave_max_u64(b);
      if (lane == 0) wmax[wid] = b;
      __syncthreads();
      unsigned long long bmax = wmax[0];
#pragma unroll
      for (int w = 1; w < 8; ++w) bmax = wmax[w] > bmax ? wmax[w] : bmax;
      if (tid == 0)
        topk_idx[row * NEG_TOPK + r] =
            (int)(0xFFFFFFFFu - (unsigned)(bmax & 0xFFFFFFFFull));
      kprev = bmax;
      __syncthreads();
    }
  }
}

// ---------------------------------------------------------------------------
// Kernel 2: per time slice t, unique valid candidates (wc==0, set semantics).
// ---------------------------------------------------------------------------
#define BM_WORDS ((V_DIM + 31) / 32)    // 1563
__global__ __launch_bounds__(256) void build_valid_kernel(const int* __restrict__ wc,
                                                          const int* __restrict__ topk,
                                                          int* __restrict__ vlist,
                                                          int* __restrict__ vcnt) {
  const int t = blockIdx.x;
  __shared__ unsigned bm[BM_WORDS];
  __shared__ int cnt;
  for (int i = threadIdx.x; i < BM_WORDS; i += 256) bm[i] = 0u;
  if (threadIdx.x == 0) cnt = 0;
  __syncthreads();
  for (int c = threadIdx.x; c < M_DIM; c += 256) {
    int w = topk[t * M_DIM + c];
    if (wc[t * V_DIM + w] == 0) {
      unsigned bit = 1u << (w & 31);
      unsigned old = atomicOr(&bm[w >> 5], bit);
      if (!(old & bit)) {
        int p = atomicAdd(&cnt, 1);
        vlist[t * M_DIM + p] = w;
      }
    }
  }
  __syncthreads();
  if (threadIdx.x == 0) vcnt[t] = cnt;
}

// ---------------------------------------------------------------------------
// Kernel 3: per row = t*K+k, logsumexp over valid candidates of
// dot(topic_emb[t,k,:], word_emb[w,:]) / 0.07.
// ---------------------------------------------------------------------------
__global__ __launch_bounds__(256) void lse_kernel(const float* __restrict__ temb,
                                                  const float* __restrict__ wemb,
                                                  const int* __restrict__ vlist,
                                                  const int* __restrict__ vcnt,
                                                  float* __restrict__ lse_out) {
  const int row  = blockIdx.x;
  const int t    = row / K_DIM;
  const int tid  = threadIdx.x;
  const int lane = tid & 63;
  const int wid  = tid >> 6;
  const int cnt  = vcnt[t];

  __shared__ float4 tv[D_DIM / 4];   // topic embedding row (broadcast reads)
  __shared__ float  sim[M_DIM];
  __shared__ float  rbuf[8];

  if (cnt == 0) {                    // uniform for the whole block
    if (tid == 0) lse_out[row] = 0.0f;
    return;
  }

  if (tid < D_DIM / 4)
    tv[tid] = ((const float4*)(temb + (size_t)row * D_DIM))[tid];
  __syncthreads();

  for (int c = tid; c < cnt; c += 256) {
    int w = vlist[t * M_DIM + c];
    const float4* wr = (const float4*)(wemb + (size_t)w * D_DIM);
    float acc = 0.f;
#pragma unroll
    for (int d = 0; d < D_DIM / 4; ++d) {
      float4 a = tv[d];
      float4 b = wr[d];
      acc = fmaf(a.x, b.x, acc);
      acc = fmaf(a.y, b.y, acc);
      acc = fmaf(a.z, b.z, acc);
      acc = fmaf(a.w, b.w, acc);
    }
    sim[c] = acc * TEMP_INV;
  }
  __syncthreads();

  float m = -3.0e38f;
  for (int c = tid; c < cnt; c += 256) m = fmaxf(m, sim[c]);
#pragma unroll
  for (int off = 32; off; off >>= 1) m = fmaxf(m, __shfl_xor(m, off, 64));
  if (lane == 0) rbuf[wid] = m;
  __syncthreads();
  m = fmaxf(fmaxf(rbuf[0], rbuf[1]), fmaxf(rbuf[2], rbuf[3]));

  float s = 0.f;
  for (int c = tid; c < cnt; c += 256) s += expf(sim[c] - m);
#pragma unroll
  for (int off = 32; off; off >>= 1) s += __shfl_xor(s, off, 64);
  if (lane == 0) rbuf[4 + wid] = s;
  __syncthreads();
  if (tid == 0) {
    float tot = rbuf[4] + rbuf[5] + rbuf[6] + rbuf[7];
    lse_out[row] = m + logf(tot);
  }
}

// ---------------------------------------------------------------------------
// Kernel 4: final scalar. loss = sum_t(mean_k lse) / count(t with any valid).
// ---------------------------------------------------------------------------
__global__ void final_kernel(const float* __restrict__ lse,
                             const int* __restrict__ vcnt,
                             float* __restrict__ out) {
  const int t = threadIdx.x;           // 64 threads, t < 20 active
  float loss = 0.f, flag = 0.f;
  if (t < T_DIM && vcnt[t] > 0) {
    float s = 0.f;
    for (int k = 0; k < K_DIM; ++k) s += lse[t * K_DIM + k];
    loss = s * (1.0f / K_DIM);
    flag = 1.f;
  }
#pragma unroll
  for (int off = 32; off; off >>= 1) {
    loss += __shfl_down(loss, off, 64);
    flag += __shfl_down(flag, off, 64);
  }
  if (t == 0)
    out[0] = (flag > 0.f) ? loss * (1.0f / fmaxf(flag, 1.f)) : 0.f;  // WEIGHT_UWE=1
}

// ---------------------------------------------------------------------------
extern "C" void kernel_launch(void* const* d_in, const int* in_sizes, int n_in,
                              void* d_out, int out_size, void* d_ws, size_t ws_size,
                              hipStream_t stream) {
  const int*   wc   = (const int*)d_in[0];    // time_wordcount [T,V] int32
  const float* beta = (const float*)d_in[1];  // beta [T,K,V] f32
  const float* temb = (const float*)d_in[2];  // topic_embeddings [T,K,D] f32
  const float* wemb = (const float*)d_in[3];  // word_embeddings [V,D] f32

  // ws layout: topk 80000B | vlist 80000B | vcnt 128B | lse 4000B
  char* ws = (char*)d_ws;
  int*   topk_idx = (int*)(ws + 0);
  int*   vlist    = (int*)(ws + 80000);
  int*   vcnt     = (int*)(ws + 160000);
  float* lse      = (float*)(ws + 160128);
  float* out      = (float*)d_out;

  topk_kernel<<<T_DIM * K_DIM, 512, 0, stream>>>(beta, topk_idx);
  build_valid_kernel<<<T_DIM, 256, 0, stream>>>(wc, topk_idx, vlist, vcnt);
  lse_kernel<<<T_DIM * K_DIM, 256, 0, stream>>>(temb, wemb, vlist, vcnt, lse);
  final_kernel<<<1, 64, 0, stream>>>(lse, vcnt, out);
}

// Round 3
// 68.802 us; speedup vs baseline: 4.2253x; 1.6387x over previous
//
#include <hip/hip_runtime.h>

#define T_DIM 20
#define K_DIM 50
#define V_DIM 50000
#define D_DIM 200
#define NEG_TOPK 20
#define M_DIM (K_DIM * NEG_TOPK)   // 1000 candidates per time slice
#define TEMP_INV (1.0f / 0.07f)
#define POOL_CAP 512
#define STATIC_THR 3.0f            // pool keeps all elements >= 3.0

// monotone key: order(key) == (value desc, index asc) matches jax.lax.top_k
__device__ __forceinline__ unsigned long long make_key(float f, int idx) {
  unsigned u  = __float_as_uint(f);
  unsigned mv = ((int)u < 0) ? ~u : (u | 0x80000000u);
  return ((unsigned long long)mv << 32) |
         (unsigned long long)(0xFFFFFFFFu - (unsigned)idx);
}

__device__ __forceinline__ unsigned long long wave_max_u64(unsigned long long k) {
#pragma unroll
  for (int off = 32; off; off >>= 1) {
    unsigned long long o = __shfl_xor(k, off, 64);
    if (o > k) k = o;
  }
  return k;
}

// ---------------------------------------------------------------------------
// Kernel 1: exact top-20 per row = t*K+k.
// Scan: 1 cmp/element, elements >= 3.0 appended to LDS pool (E[|pool|]~67).
// If 20 <= |pool| <= 512 the exact top-20 is in the pool (if >=20 elements
// are >= thr, the 20th-largest >= thr). Selection runs on wave 0 ONLY:
// 8 keys/lane in registers, 20 rounds of barrier-free wave-max with
// strict-key exclusion. Waves 1..7 exit after the scan. Fallback
// (<20 or >512 pooled): exact 20-round block-wide rescan (L2-hot).
// ---------------------------------------------------------------------------
__global__ __launch_bounds__(512) void topk_kernel(const float* __restrict__ beta,
                                                   int* __restrict__ topk_idx) {
  const int row  = blockIdx.x;          // 0..999
  const int tid  = threadIdx.x;
  const int lane = tid & 63;
  const int wid  = tid >> 6;
  const float4* __restrict__ b4 = (const float4*)(beta + (size_t)row * V_DIM);

  __shared__ unsigned long long pool[POOL_CAP];
  __shared__ int cnt;
  __shared__ unsigned long long wmax[8];
  if (tid == 0) cnt = 0;
  __syncthreads();

  // ---- scan: 1 compare per element, rare append ----
  for (int i = tid; i < V_DIM / 4; i += 512) {
    float4 v = b4[i];
    const int base = i * 4;
#pragma unroll
    for (int e = 0; e < 4; ++e) {
      float f = (e == 0) ? v.x : (e == 1) ? v.y : (e == 2) ? v.z : v.w;
      if (f >= STATIC_THR) {
        int p = atomicAdd(&cnt, 1);
        if (p < POOL_CAP) pool[p] = make_key(f, base + e);
      }
    }
  }
  __syncthreads();
  const int count = cnt;

  if (count >= NEG_TOPK && count <= POOL_CAP) {
    if (wid != 0) return;              // selection is wave-0-only, no barriers
    unsigned long long kk[8];
#pragma unroll
    for (int j = 0; j < 8; ++j) {
      int p = lane + (j << 6);
      kk[j] = (p < count) ? pool[p] : 0ull;
    }
    unsigned long long kprev = ~0ull;
    for (int r = 0; r < NEG_TOPK; ++r) {
      unsigned long long b = 0ull;
#pragma unroll
      for (int j = 0; j < 8; ++j)
        if (kk[j] < kprev && kk[j] > b) b = kk[j];
      b = wave_max_u64(b);
      if (lane == 0)
        topk_idx[row * NEG_TOPK + r] =
            (int)(0xFFFFFFFFu - (unsigned)(b & 0xFFFFFFFFull));
      kprev = b;
    }
  } else {
    // ---- fallback: 20 rounds of block argmax over the row (L2-hot) ----
    unsigned long long kprev = ~0ull;
    for (int r = 0; r < NEG_TOPK; ++r) {
      unsigned long long b = 0ull;
      for (int i = tid; i < V_DIM / 4; i += 512) {
        float4 v = b4[i];
        const int base = i * 4;
#pragma unroll
        for (int e = 0; e < 4; ++e) {
          float f = (e == 0) ? v.x : (e == 1) ? v.y : (e == 2) ? v.z : v.w;
          unsigned long long k = make_key(f, base + e);
          if (k < kprev && k > b) b = k;
        }
      }
      b = wave_max_u64(b);
      if (lane == 0) wmax[wid] = b;
      __syncthreads();
      unsigned long long bmax = wmax[0];
#pragma unroll
      for (int w = 1; w < 8; ++w) bmax = wmax[w] > bmax ? wmax[w] : bmax;
      if (tid == 0)
        topk_idx[row * NEG_TOPK + r] =
            (int)(0xFFFFFFFFu - (unsigned)(bmax & 0xFFFFFFFFull));
      kprev = bmax;
      __syncthreads();
    }
  }
}

// ---------------------------------------------------------------------------
// Kernel 2: per time slice t, unique valid candidates (wc==0, set semantics;
// which duplicate survives is irrelevant — identical sim rows).
// ---------------------------------------------------------------------------
#define BM_WORDS ((V_DIM + 31) / 32)    // 1563
__global__ __launch_bounds__(256) void build_valid_kernel(const int* __restrict__ wc,
                                                          const int* __restrict__ topk,
                                                          int* __restrict__ vlist,
                                                          int* __restrict__ vcnt) {
  const int t = blockIdx.x;
  __shared__ unsigned bm[BM_WORDS];
  __shared__ int cnt;
  for (int i = threadIdx.x; i < BM_WORDS; i += 256) bm[i] = 0u;
  if (threadIdx.x == 0) cnt = 0;
  __syncthreads();
  for (int c = threadIdx.x; c < M_DIM; c += 256) {
    int w = topk[t * M_DIM + c];
    if (wc[t * V_DIM + w] == 0) {
      unsigned bit = 1u << (w & 31);
      unsigned old = atomicOr(&bm[w >> 5], bit);
      if (!(old & bit)) {
        int p = atomicAdd(&cnt, 1);
        vlist[t * M_DIM + p] = w;
      }
    }
  }
  __syncthreads();
  if (threadIdx.x == 0) vcnt[t] = cnt;
}

// ---------------------------------------------------------------------------
// Kernel 3: per row = t*K+k, logsumexp over valid candidates of
// dot(topic_emb[t,k,:], word_emb[w,:]) / 0.07.
// Gather is 8-lane-cooperative: lanes 8g..8g+7 read 128B-contiguous chunks
// of candidate row (c0 + g) -> 8 rows per wave-load, coalesced; dot reduced
// across the 8-lane group via shfl_xor.
// ---------------------------------------------------------------------------
__global__ __launch_bounds__(256) void lse_kernel(const float* __restrict__ temb,
                                                  const float* __restrict__ wemb,
                                                  const int* __restrict__ vlist,
                                                  const int* __restrict__ vcnt,
                                                  float* __restrict__ lse_out) {
  const int row  = blockIdx.x;
  const int t    = row / K_DIM;
  const int tid  = threadIdx.x;
  const int lane = tid & 63;
  const int wid  = tid >> 6;
  const int cnt  = vcnt[t];

  __shared__ float4 tvs[D_DIM / 4];  // 50 float4: topic embedding row
  __shared__ float  sim[M_DIM];
  __shared__ float  rbuf[8];

  if (cnt == 0) {
    if (tid == 0) lse_out[row] = 0.0f;
    return;
  }

  if (tid < D_DIM / 4)
    tvs[tid] = ((const float4*)(temb + (size_t)row * D_DIM))[tid];
  __syncthreads();

  const int l7 = lane & 7;
  const int g  = lane >> 3;          // candidate sub-slot 0..7 within wave
  for (int c0 = wid * 8; c0 < cnt; c0 += 32) {
    const int c = c0 + g;
    float acc = 0.f;
    if (c < cnt) {
      const int w = vlist[t * M_DIM + c];
      const float4* __restrict__ wr = (const float4*)(wemb + (size_t)w * D_DIM);
#pragma unroll
      for (int m = 0; m < 6; ++m) {        // d = l7 + 8m, always < 50 for m<6
        const int d = l7 + (m << 3);
        float4 a = tvs[d];
        float4 b = wr[d];
        acc = fmaf(a.x, b.x, acc);
        acc = fmaf(a.y, b.y, acc);
        acc = fmaf(a.z, b.z, acc);
        acc = fmaf(a.w, b.w, acc);
      }
      if (l7 < 2) {                        // d = l7 + 48 in {48,49}
        const int d = l7 + 48;
        float4 a = tvs[d];
        float4 b = wr[d];
        acc = fmaf(a.x, b.x, acc);
        acc = fmaf(a.y, b.y, acc);
        acc = fmaf(a.z, b.z, acc);
        acc = fmaf(a.w, b.w, acc);
      }
    }
    acc += __shfl_xor(acc, 1, 64);
    acc += __shfl_xor(acc, 2, 64);
    acc += __shfl_xor(acc, 4, 64);
    if (l7 == 0 && c < cnt) sim[c] = acc * TEMP_INV;
  }
  __syncthreads();

  float m = -3.0e38f;
  for (int c = tid; c < cnt; c += 256) m = fmaxf(m, sim[c]);
#pragma unroll
  for (int off = 32; off; off >>= 1) m = fmaxf(m, __shfl_xor(m, off, 64));
  if (lane == 0) rbuf[wid] = m;
  __syncthreads();
  m = fmaxf(fmaxf(rbuf[0], rbuf[1]), fmaxf(rbuf[2], rbuf[3]));

  float s = 0.f;
  for (int c = tid; c < cnt; c += 256) s += expf(sim[c] - m);
#pragma unroll
  for (int off = 32; off; off >>= 1) s += __shfl_xor(s, off, 64);
  if (lane == 0) rbuf[4 + wid] = s;
  __syncthreads();
  if (tid == 0) {
    float tot = rbuf[4] + rbuf[5] + rbuf[6] + rbuf[7];
    lse_out[row] = m + logf(tot);
  }
}

// ---------------------------------------------------------------------------
// Kernel 4: final scalar. loss = sum_t(mean_k lse) / count(t with any valid).
// ---------------------------------------------------------------------------
__global__ void final_kernel(const float* __restrict__ lse,
                             const int* __restrict__ vcnt,
                             float* __restrict__ out) {
  const int t = threadIdx.x;           // 64 threads, t < 20 active
  float loss = 0.f, flag = 0.f;
  if (t < T_DIM && vcnt[t] > 0) {
    float s = 0.f;
    for (int k = 0; k < K_DIM; ++k) s += lse[t * K_DIM + k];
    loss = s * (1.0f / K_DIM);
    flag = 1.f;
  }
#pragma unroll
  for (int off = 32; off; off >>= 1) {
    loss += __shfl_down(loss, off, 64);
    flag += __shfl_down(flag, off, 64);
  }
  if (t == 0)
    out[0] = (flag > 0.f) ? loss * (1.0f / fmaxf(flag, 1.f)) : 0.f;  // WEIGHT_UWE=1
}

// ---------------------------------------------------------------------------
extern "C" void kernel_launch(void* const* d_in, const int* in_sizes, int n_in,
                              void* d_out, int out_size, void* d_ws, size_t ws_size,
                              hipStream_t stream) {
  const int*   wc   = (const int*)d_in[0];    // time_wordcount [T,V] int32
  const float* beta = (const float*)d_in[1];  // beta [T,K,V] f32
  const float* temb = (const float*)d_in[2];  // topic_embeddings [T,K,D] f32
  const float* wemb = (const float*)d_in[3];  // word_embeddings [V,D] f32

  // ws layout: topk 80000B | vlist 80000B | vcnt 128B | lse 4000B
  char* ws = (char*)d_ws;
  int*   topk_idx = (int*)(ws + 0);
  int*   vlist    = (int*)(ws + 80000);
  int*   vcnt     = (int*)(ws + 160000);
  float* lse      = (float*)(ws + 160128);
  float* out      = (float*)d_out;

  topk_kernel<<<T_DIM * K_DIM, 512, 0, stream>>>(beta, topk_idx);
  build_valid_kernel<<<T_DIM, 256, 0, stream>>>(wc, topk_idx, vlist, vcnt);
  lse_kernel<<<T_DIM * K_DIM, 256, 0, stream>>>(temb, wemb, vlist, vcnt, lse);
  final_kernel<<<1, 64, 0, stream>>>(lse, vcnt, out);
}